// Round 2
// baseline (66.644 us; speedup 1.0000x reference)
//
#include <hip/hip_runtime.h>

// MeanAggregator: out[i, :] = mean over e in [i*17, i*17+17) of feat[edge_dst[e], :]
// Shapes fixed by the reference: D = 128, DEG+1 = 17, B = E / 17.
//
// Layout: one block = 256 threads = 8 nodes x 32 lanes.
// Each lane owns one float4 chunk (16 B) of the 128-float row -> a gathered
// row is read as 32 lanes x 16 B = 512 B, fully coalesced.
//
// Round-2 change: issue ALL 17 gather loads into registers before reducing
// (load-all-then-reduce) to maximize memory-level parallelism -- the gather
// is latency-bound on L2/L3 hits (steady-state FETCH~0, table L3-resident),
// not HBM-bound. __launch_bounds__(256,4) caps VGPRs at 128 (16 waves/CU).

#define D_DIM 128
#define DEGP1 17
#define NODES_PER_BLOCK 8

__global__ __launch_bounds__(256, 4) void mean_agg_kernel(
    const float* __restrict__ feat,      // [N_TOTAL, 128]
    const int*   __restrict__ edge_dst,  // [E]
    float*       __restrict__ out,       // [B, 128]
    int B)
{
    __shared__ int s_idx[NODES_PER_BLOCK * DEGP1];

    const int base_node = blockIdx.x * NODES_PER_BLOCK;

    // Cooperatively load this block's edge indices (8*17 = 136 ints).
    for (int t = threadIdx.x; t < NODES_PER_BLOCK * DEGP1; t += 256) {
        const int n = base_node + t / DEGP1;
        if (n < B) s_idx[t] = edge_dst[(size_t)n * DEGP1 + (t % DEGP1)];
    }
    __syncthreads();

    const int local_node = threadIdx.x >> 5;          // 0..7
    const int node = base_node + local_node;
    if (node >= B) return;

    const int lane4 = threadIdx.x & 31;               // float4 chunk 0..31
    const int col = lane4 * 4;                        // starting float column

    const int* idx = &s_idx[local_node * DEGP1];

    // Pull all 17 row indices out of LDS first (broadcast reads, conflict-free),
    // then issue all 17 global loads back-to-back so they are simultaneously
    // in flight before the first accumulation forces a waitcnt.
    int rows[DEGP1];
    #pragma unroll
    for (int e = 0; e < DEGP1; ++e) rows[e] = idx[e];

    float4 v[DEGP1];
    #pragma unroll
    for (int e = 0; e < DEGP1; ++e) {
        v[e] = *reinterpret_cast<const float4*>(
            &feat[(size_t)rows[e] * D_DIM + col]);
    }

    // Tree reduction (shorter dependency chain than serial adds).
    #pragma unroll
    for (int stride = 1; stride < DEGP1; stride *= 2) {
        #pragma unroll
        for (int e = 0; e + stride < DEGP1; e += 2 * stride) {
            v[e].x += v[e + stride].x;
            v[e].y += v[e + stride].y;
            v[e].z += v[e + stride].z;
            v[e].w += v[e + stride].w;
        }
    }

    const float inv = 1.0f / (float)DEGP1;
    float4 r = make_float4(v[0].x * inv, v[0].y * inv, v[0].z * inv, v[0].w * inv);
    *reinterpret_cast<float4*>(&out[(size_t)node * D_DIM + col]) = r;
}

extern "C" void kernel_launch(void* const* d_in, const int* in_sizes, int n_in,
                              void* d_out, int out_size, void* d_ws, size_t ws_size,
                              hipStream_t stream)
{
    const float* feat     = (const float*)d_in[0];  // features [N_TOTAL*128]
    // d_in[1] = edge_seg (unused: segments are contiguous fixed-size 17)
    const int*   edge_dst = (const int*)d_in[2];    // [E]
    // d_in[3] = num_nodes scalar on device; derive B from sizes instead.

    const int E = in_sizes[2];
    const int B = E / DEGP1;                        // 850000 / 17 = 50000

    float* out = (float*)d_out;

    const int grid = (B + NODES_PER_BLOCK - 1) / NODES_PER_BLOCK;
    mean_agg_kernel<<<grid, 256, 0, stream>>>(feat, edge_dst, out, B);
}

// Round 3
// 66.180 us; speedup vs baseline: 1.0070x; 1.0070x over previous
//
#include <hip/hip_runtime.h>

// MeanAggregator: out[i, :] = mean over e in [i*17, i*17+17) of feat[edge_dst[e], :]
// Shapes fixed by the reference: D = 128, DEG+1 = 17, B = E / 17.
//
// Layout: one block = 256 threads = 8 nodes x 32 lanes; lane owns one float4
// chunk of the 128-float row (wave = 2 nodes, 1 KB per load instruction).
//
// Round-3 change: FORCE all 17 gather loads to be simultaneously in flight.
// Round 2 showed the compiler re-serialized the load-all pattern (VGPR=32 ->
// ~1.3 outstanding loads/wave; Little's law matches the observed 3.4 TB/s at
// ~500cy L3-hit latency). __builtin_amdgcn_sched_barrier(0) between the load
// loop and the reduction pins all loads before all adds, forcing ~68 live
// VGPRs of load data -> 17 outstanding 1 KB loads per wave.

#define D_DIM 128
#define DEGP1 17
#define NODES_PER_BLOCK 8

__global__ __launch_bounds__(256, 4) void mean_agg_kernel(
    const float* __restrict__ feat,      // [N_TOTAL, 128]
    const int*   __restrict__ edge_dst,  // [E]
    float*       __restrict__ out,       // [B, 128]
    int B)
{
    __shared__ int s_idx[NODES_PER_BLOCK * DEGP1];

    const int base_node = blockIdx.x * NODES_PER_BLOCK;

    // Cooperatively load this block's edge indices (8*17 = 136 ints).
    for (int t = threadIdx.x; t < NODES_PER_BLOCK * DEGP1; t += 256) {
        const int n = base_node + t / DEGP1;
        if (n < B) s_idx[t] = edge_dst[(size_t)n * DEGP1 + (t % DEGP1)];
    }
    __syncthreads();

    const int local_node = threadIdx.x >> 5;          // 0..7
    const int node = base_node + local_node;
    if (node >= B) return;

    const int lane4 = threadIdx.x & 31;               // float4 chunk 0..31
    const int col = lane4 * 4;                        // starting float column

    const int* idx = &s_idx[local_node * DEGP1];

    int rows[DEGP1];
    #pragma unroll
    for (int e = 0; e < DEGP1; ++e) rows[e] = idx[e];

    // Issue ALL 17 independent gather loads...
    float4 v[DEGP1];
    #pragma unroll
    for (int e = 0; e < DEGP1; ++e) {
        v[e] = *reinterpret_cast<const float4*>(
            &feat[(size_t)rows[e] * D_DIM + col]);
    }
    // ...and forbid the scheduler from sinking any arithmetic above this
    // point: all 17 loads must be issued (and their results live) before
    // the first add. This is what creates the MLP.
    __builtin_amdgcn_sched_barrier(0);

    // Tree reduction (short dependency chain).
    #pragma unroll
    for (int stride = 1; stride < DEGP1; stride *= 2) {
        #pragma unroll
        for (int e = 0; e + stride < DEGP1; e += 2 * stride) {
            v[e].x += v[e + stride].x;
            v[e].y += v[e + stride].y;
            v[e].z += v[e + stride].z;
            v[e].w += v[e + stride].w;
        }
    }

    const float inv = 1.0f / (float)DEGP1;
    float4 r = make_float4(v[0].x * inv, v[0].y * inv, v[0].z * inv, v[0].w * inv);
    *reinterpret_cast<float4*>(&out[(size_t)node * D_DIM + col]) = r;
}

extern "C" void kernel_launch(void* const* d_in, const int* in_sizes, int n_in,
                              void* d_out, int out_size, void* d_ws, size_t ws_size,
                              hipStream_t stream)
{
    const float* feat     = (const float*)d_in[0];  // features [N_TOTAL*128]
    // d_in[1] = edge_seg (unused: segments are contiguous fixed-size 17)
    const int*   edge_dst = (const int*)d_in[2];    // [E]
    // d_in[3] = num_nodes scalar on device; derive B from sizes instead.

    const int E = in_sizes[2];
    const int B = E / DEGP1;                        // 850000 / 17 = 50000

    float* out = (float*)d_out;

    const int grid = (B + NODES_PER_BLOCK - 1) / NODES_PER_BLOCK;
    mean_agg_kernel<<<grid, 256, 0, stream>>>(feat, edge_dst, out, B);
}

// Round 4
// 65.902 us; speedup vs baseline: 1.0113x; 1.0042x over previous
//
#include <hip/hip_runtime.h>

// MeanAggregator: out[i, :] = mean over e in [i*17, i*17+17) of feat[edge_dst[e], :]
// Shapes fixed by the reference: D = 128, DEG+1 = 17, B = E / 17.
//
// Layout: one block = 256 threads = 8 nodes x 32 lanes; lane owns one float4
// chunk of the 128-float row (gathered row = 32 lanes x 16 B = 512 B, coalesced).
//
// Round-4 change: the compiler defeated load-all-then-reduce twice (VGPR stuck
// at 36 -> ~0.6 loads in flight/wave, latency-bound at 3.5 TB/s). Force MLP
// with volatile inline-asm global_load_dwordx4 (saddr form: 32-bit voffset +
// SGPR base), one s_waitcnt vmcnt(0) + sched_barrier(0) fence (rule #18),
// then reduce. 17 outstanding 1 KB loads per wave, ~100 VGPRs live.

#define D_DIM 128
#define DEGP1 17
#define NODES_PER_BLOCK 8

typedef float f32x4 __attribute__((ext_vector_type(4)));

__global__ __launch_bounds__(256, 4) void mean_agg_kernel(
    const float* __restrict__ feat,      // [N_TOTAL, 128]
    const int*   __restrict__ edge_dst,  // [E]
    float*       __restrict__ out,       // [B, 128]
    int B)
{
    __shared__ int s_idx[NODES_PER_BLOCK * DEGP1];

    const int base_node = blockIdx.x * NODES_PER_BLOCK;

    // Cooperatively load this block's edge indices (8*17 = 136 ints).
    for (int t = threadIdx.x; t < NODES_PER_BLOCK * DEGP1; t += 256) {
        const int n = base_node + t / DEGP1;
        if (n < B) s_idx[t] = edge_dst[(size_t)n * DEGP1 + (t % DEGP1)];
    }
    __syncthreads();

    const int local_node = threadIdx.x >> 5;          // 0..7
    const int node = base_node + local_node;
    if (node >= B) return;

    const int lane4 = threadIdx.x & 31;               // float4 chunk 0..31
    const unsigned col_bytes = (unsigned)(lane4 * 16); // byte offset within row

    const int* idx = &s_idx[local_node * DEGP1];

    // 32-bit byte offsets into feat (max = 100000*512 + 496 < 2^32).
    unsigned off[DEGP1];
    #pragma unroll
    for (int e = 0; e < DEGP1; ++e)
        off[e] = (unsigned)idx[e] * (unsigned)(D_DIM * 4) + col_bytes;

    // Issue ALL 17 gathers as volatile asm: the compiler cannot interleave
    // arithmetic or insert per-load waitcnts, and the "=&v" outputs force
    // 17 float4 live ranges -> 17 loads simultaneously in flight.
    f32x4 v[DEGP1];
    #pragma unroll
    for (int e = 0; e < DEGP1; ++e) {
        asm volatile("global_load_dwordx4 %0, %1, %2"
                     : "=&v"(v[e])
                     : "v"(off[e]), "s"(feat));
    }
    // Single drain, then fence so no consumer is scheduled above it (rule #18).
    asm volatile("s_waitcnt vmcnt(0)" ::: "memory");
    __builtin_amdgcn_sched_barrier(0);

    // Tree reduction (short dependency chain).
    #pragma unroll
    for (int stride = 1; stride < DEGP1; stride *= 2) {
        #pragma unroll
        for (int e = 0; e + stride < DEGP1; e += 2 * stride) {
            v[e] += v[e + stride];
        }
    }

    const float inv = 1.0f / (float)DEGP1;
    f32x4 r = v[0] * inv;
    *reinterpret_cast<f32x4*>(&out[(size_t)node * D_DIM + lane4 * 4]) = r;
}

extern "C" void kernel_launch(void* const* d_in, const int* in_sizes, int n_in,
                              void* d_out, int out_size, void* d_ws, size_t ws_size,
                              hipStream_t stream)
{
    const float* feat     = (const float*)d_in[0];  // features [N_TOTAL*128]
    // d_in[1] = edge_seg (unused: segments are contiguous fixed-size 17)
    const int*   edge_dst = (const int*)d_in[2];    // [E]
    // d_in[3] = num_nodes scalar on device; derive B from sizes instead.

    const int E = in_sizes[2];
    const int B = E / DEGP1;                        // 850000 / 17 = 50000

    float* out = (float*)d_out;

    const int grid = (B + NODES_PER_BLOCK - 1) / NODES_PER_BLOCK;
    mean_agg_kernel<<<grid, 256, 0, stream>>>(feat, edge_dst, out, B);
}

// Round 5
// 65.027 us; speedup vs baseline: 1.0249x; 1.0135x over previous
//
#include <hip/hip_runtime.h>

// MeanAggregator: out[i, :] = mean over e in [i*17, i*17+17) of feat[edge_dst[e], :]
// Shapes fixed by the reference: D = 128, DEG+1 = 17, B = E / 17.
//
// Layout: one block = 256 threads = 8 nodes x 32 lanes; lane owns one float4
// chunk of the 128-float row (gathered row = 32 lanes x 16 B = 512 B, coalesced).
//
// Round-5: MLP forced via ONE asm volatile mega-block containing all 17
// global_load_dwordx4 (saddr form) AND the single s_waitcnt vmcnt(0).
// Rounds 2-4 showed the compiler defeats every multi-statement formulation
// (VGPR stuck at 36 -> ~1 load in flight). Inside one block it cannot
// interleave or re-allocate: 17 early-clobber f32x4 outputs = 68 live VGPRs,
// 17 x 1 KB loads outstanding per wave.

#define D_DIM 128
#define DEGP1 17
#define NODES_PER_BLOCK 8

typedef float f32x4 __attribute__((ext_vector_type(4)));

__global__ __launch_bounds__(256, 4) void mean_agg_kernel(
    const float* __restrict__ feat,      // [N_TOTAL, 128]
    const int*   __restrict__ edge_dst,  // [E]
    float*       __restrict__ out,       // [B, 128]
    int B)
{
    __shared__ int s_idx[NODES_PER_BLOCK * DEGP1];

    const int base_node = blockIdx.x * NODES_PER_BLOCK;

    for (int t = threadIdx.x; t < NODES_PER_BLOCK * DEGP1; t += 256) {
        const int n = base_node + t / DEGP1;
        if (n < B) s_idx[t] = edge_dst[(size_t)n * DEGP1 + (t % DEGP1)];
    }
    __syncthreads();

    const int local_node = threadIdx.x >> 5;          // 0..7
    const int node = base_node + local_node;
    if (node >= B) return;

    const int lane4 = threadIdx.x & 31;               // float4 chunk 0..31
    const unsigned col_bytes = (unsigned)(lane4 * 16);

    const int* idx = &s_idx[local_node * DEGP1];

    // 32-bit byte offsets into feat (max = 100000*512 + 496 < 2^32).
    unsigned off[DEGP1];
    #pragma unroll
    for (int e = 0; e < DEGP1; ++e)
        off[e] = (unsigned)idx[e] * (unsigned)(D_DIM * 4) + col_bytes;

    f32x4 v0, v1, v2, v3, v4, v5, v6, v7, v8, v9, v10, v11, v12, v13, v14, v15, v16;

    // One block: 17 back-to-back loads, one drain. Early-clobber outputs
    // guarantee dest regs are disjoint from all offset regs (loads are async;
    // data return for load i may precede issue of load j>i).
    asm volatile(
        "global_load_dwordx4 %0,  %17, %34\n\t"
        "global_load_dwordx4 %1,  %18, %34\n\t"
        "global_load_dwordx4 %2,  %19, %34\n\t"
        "global_load_dwordx4 %3,  %20, %34\n\t"
        "global_load_dwordx4 %4,  %21, %34\n\t"
        "global_load_dwordx4 %5,  %22, %34\n\t"
        "global_load_dwordx4 %6,  %23, %34\n\t"
        "global_load_dwordx4 %7,  %24, %34\n\t"
        "global_load_dwordx4 %8,  %25, %34\n\t"
        "global_load_dwordx4 %9,  %26, %34\n\t"
        "global_load_dwordx4 %10, %27, %34\n\t"
        "global_load_dwordx4 %11, %28, %34\n\t"
        "global_load_dwordx4 %12, %29, %34\n\t"
        "global_load_dwordx4 %13, %30, %34\n\t"
        "global_load_dwordx4 %14, %31, %34\n\t"
        "global_load_dwordx4 %15, %32, %34\n\t"
        "global_load_dwordx4 %16, %33, %34\n\t"
        "s_waitcnt vmcnt(0)"
        : "=&v"(v0), "=&v"(v1), "=&v"(v2), "=&v"(v3), "=&v"(v4), "=&v"(v5),
          "=&v"(v6), "=&v"(v7), "=&v"(v8), "=&v"(v9), "=&v"(v10), "=&v"(v11),
          "=&v"(v12), "=&v"(v13), "=&v"(v14), "=&v"(v15), "=&v"(v16)
        : "v"(off[0]), "v"(off[1]), "v"(off[2]), "v"(off[3]), "v"(off[4]),
          "v"(off[5]), "v"(off[6]), "v"(off[7]), "v"(off[8]), "v"(off[9]),
          "v"(off[10]), "v"(off[11]), "v"(off[12]), "v"(off[13]), "v"(off[14]),
          "v"(off[15]), "v"(off[16]), "s"(feat)
        : "memory");

    // Tree reduction (short dependency chain), then scale.
    f32x4 a0 = v0 + v1;   f32x4 a1 = v2 + v3;   f32x4 a2 = v4 + v5;
    f32x4 a3 = v6 + v7;   f32x4 a4 = v8 + v9;   f32x4 a5 = v10 + v11;
    f32x4 a6 = v12 + v13; f32x4 a7 = v14 + v15;
    f32x4 b0 = a0 + a1;   f32x4 b1 = a2 + a3;   f32x4 b2 = a4 + a5;
    f32x4 b3 = a6 + a7;
    f32x4 c0 = b0 + b1;   f32x4 c1 = b2 + b3;
    f32x4 s  = c0 + c1 + v16;

    const float inv = 1.0f / (float)DEGP1;
    f32x4 r = s * inv;
    *reinterpret_cast<f32x4*>(&out[(size_t)node * D_DIM + lane4 * 4]) = r;
}

extern "C" void kernel_launch(void* const* d_in, const int* in_sizes, int n_in,
                              void* d_out, int out_size, void* d_ws, size_t ws_size,
                              hipStream_t stream)
{
    const float* feat     = (const float*)d_in[0];  // features [N_TOTAL*128]
    // d_in[1] = edge_seg (unused: segments are contiguous fixed-size 17)
    const int*   edge_dst = (const int*)d_in[2];    // [E]
    // d_in[3] = num_nodes scalar; derive B from sizes instead.

    const int E = in_sizes[2];
    const int B = E / DEGP1;                        // 850000 / 17 = 50000

    float* out = (float*)d_out;

    const int grid = (B + NODES_PER_BLOCK - 1) / NODES_PER_BLOCK;
    mean_agg_kernel<<<grid, 256, 0, stream>>>(feat, edge_dst, out, B);
}